// Round 11
// baseline (93.900 us; speedup 1.0000x reference)
//
#include <hip/hip_runtime.h>
#include <stdint.h>
#include <float.h>
#include <math.h>

// Problem constants (b_n=2, f_num=4, N=50, C_in=256, C=64, h=200, w=336)
#define HW_TOT 67200   // h*w = 320 * 210
#define NBF 8          // n = b_n*f_num
#define CO 64          // C
#define CI 256         // C_in
#define NN 50          // N
#define KK 200         // K = N*f_num
#define BN 2           // b_n
#define PT 320         // p-tile per block (210 blocks/b, exact)
#define CHK 32         // c-rows per phase (2 phases)

// ---------------------------------------------------------------------------
// Threefry-2x32, 20 rounds (JAX partitionable threefry semantics) — verified R1
// ---------------------------------------------------------------------------
__device__ __forceinline__ uint32_t rotl32(uint32_t v, int n) {
  return (v << n) | (v >> (32 - n));
}

__device__ void tf2x32(uint32_t k0, uint32_t k1, uint32_t x0, uint32_t x1,
                       uint32_t& o0, uint32_t& o1) {
  const uint32_t ks2 = k0 ^ k1 ^ 0x1BD11BDAu;
  x0 += k0; x1 += k1;
  x0 += x1; x1 = rotl32(x1, 13); x1 ^= x0;
  x0 += x1; x1 = rotl32(x1, 15); x1 ^= x0;
  x0 += x1; x1 = rotl32(x1, 26); x1 ^= x0;
  x0 += x1; x1 = rotl32(x1, 6);  x1 ^= x0;
  x0 += k1; x1 += ks2 + 1u;
  x0 += x1; x1 = rotl32(x1, 17); x1 ^= x0;
  x0 += x1; x1 = rotl32(x1, 29); x1 ^= x0;
  x0 += x1; x1 = rotl32(x1, 16); x1 ^= x0;
  x0 += x1; x1 = rotl32(x1, 24); x1 ^= x0;
  x0 += ks2; x1 += k0 + 2u;
  x0 += x1; x1 = rotl32(x1, 13); x1 ^= x0;
  x0 += x1; x1 = rotl32(x1, 15); x1 ^= x0;
  x0 += x1; x1 = rotl32(x1, 26); x1 ^= x0;
  x0 += x1; x1 = rotl32(x1, 6);  x1 ^= x0;
  x0 += k0; x1 += k1 + 3u;
  x0 += x1; x1 = rotl32(x1, 17); x1 ^= x0;
  x0 += x1; x1 = rotl32(x1, 29); x1 ^= x0;
  x0 += x1; x1 = rotl32(x1, 16); x1 ^= x0;
  x0 += x1; x1 = rotl32(x1, 24); x1 ^= x0;
  x0 += k1; x1 += ks2 + 4u;
  x0 += x1; x1 = rotl32(x1, 13); x1 ^= x0;
  x0 += x1; x1 = rotl32(x1, 15); x1 ^= x0;
  x0 += x1; x1 = rotl32(x1, 26); x1 ^= x0;
  x0 += x1; x1 = rotl32(x1, 6);  x1 ^= x0;
  o0 = x0 + ks2;
  o1 = x1 + k0 + 5u;
}

__device__ int jax_r(int b, int k) {
  uint32_t k1a, k1b, k2a, k2b, h0, h1, l0, l1;
  tf2x32(0u, 42u, 0u, 0u, k1a, k1b);  // split: subkey 0
  tf2x32(0u, 42u, 0u, 1u, k2a, k2b);  // split: subkey 1
  const uint32_t idx = (uint32_t)(b * KK + k);
  tf2x32(k1a, k1b, 0u, idx, h0, h1);
  tf2x32(k2a, k2b, 0u, idx, l0, l1);
  const uint32_t hb = h0 ^ h1, lb = l0 ^ l1;
  return (int)(((hb % 3u) + (lb % 3u)) % 3u);
}

// ---------------------------------------------------------------------------
// Kernel 1: mw[b][d][n] = bias[d] + sum_ci idx_feat[b][ci][n] * weight[d][ci]
// ---------------------------------------------------------------------------
__global__ __launch_bounds__(256) void k_mw(const float* __restrict__ idx_feat,
                                            const float* __restrict__ weight,
                                            const float* __restrict__ bias,
                                            float* __restrict__ mw) {
  const int tid = blockIdx.x * 256 + threadIdx.x;
  if (tid >= NBF * CO * NN) return;
  const int n = tid % NN;
  const int rest = tid / NN;
  const int d = rest % CO;
  const int b = rest / CO;
  float acc = bias[d];
  const float* feat = idx_feat + (size_t)(b * CI) * NN + n;  // stride NN per ci
  const float* wrow = weight + d * CI;
  #pragma unroll 8
  for (int ci = 0; ci < CI; ++ci)
    acc = fmaf(feat[ci * NN], wrow[ci], acc);
  mw[tid] = acc;  // layout [b][d][n]
}

// ---------------------------------------------------------------------------
// Kernel 2: contrastive loss partials. 16 blocks = 2 b * 8 chunks of 25 k.
// ---------------------------------------------------------------------------
__device__ __forceinline__ float waveMax(float v) {
  #pragma unroll
  for (int o = 32; o > 0; o >>= 1) v = fmaxf(v, __shfl_down(v, o));
  return v;
}
__device__ __forceinline__ float waveSum(float v) {
  #pragma unroll
  for (int o = 32; o > 0; o >>= 1) v += __shfl_down(v, o);
  return v;
}

__global__ __launch_bounds__(256) void k_loss(const float* __restrict__ mw,
                                              float* __restrict__ partial) {
  __shared__ __align__(16) float m_lds[KK][68];  // padded rows (54.4 KB)
  __shared__ float red[8];
  __shared__ float pos_sh;
  __shared__ int rvals[32];

  const int b = blockIdx.x >> 3;
  const int chunk = blockIdx.x & 7;
  const int t = threadIdx.x;
  const int wid = t >> 6, lane = t & 63;
  const int kbase = chunk * 25;

  if (t < 25) rvals[t] = jax_r(b, kbase + t);

  float row[CO];
  if (t < KK) {
    const int f = t & 3, ni = t >> 2;
    const float* src = mw + (size_t)((b * 4 + f) * CO) * NN + ni;  // stride NN per c
    float ssq = 0.f;
    #pragma unroll
    for (int c = 0; c < CO; ++c) { const float v = src[c * NN]; row[c] = v; ssq += v * v; }
    const float inv = 1.0f / fmaxf(sqrtf(ssq), 1e-12f);
    #pragma unroll
    for (int c = 0; c < CO; ++c) { row[c] *= inv; m_lds[t][c] = row[c]; }
  }
  __syncthreads();

  float part = 0.f;
  for (int kk = 0; kk < 25; ++kk) {
    const int k = kbase + kk;
    const int g = k >> 2, fo = k & 3;
    const int r = rvals[kk];
    const int pos_off = (r >= fo) ? r + 1 : r;
    const int pos_col = (g << 2) + pos_off;
    const int last_neg = (g == NN - 1) ? (KK - 5) : (KK - 1);  // 195 or 199

    float dot = 0.f;
    if (t < KK) {
      const float4* mk = reinterpret_cast<const float4*>(&m_lds[k][0]);  // broadcast
      #pragma unroll
      for (int c4 = 0; c4 < 16; ++c4) {
        const float4 a = mk[c4];
        dot = fmaf(a.x, row[4 * c4 + 0], dot);
        dot = fmaf(a.y, row[4 * c4 + 1], dot);
        dot = fmaf(a.z, row[4 * c4 + 2], dot);
        dot = fmaf(a.w, row[4 * c4 + 3], dot);
      }
    }
    const float logit = dot * (1.0f / 0.07f);

    float wgt = 0.f;
    if (t < KK) {
      if (t == pos_col) wgt = 1.f;
      else if ((t >> 2) != g) wgt = (t == last_neg) ? 4.f : 1.f;
    }
    const bool valid = wgt > 0.f;

    const float wmax = waveMax(valid ? logit : -FLT_MAX);
    if (lane == 0) red[wid] = wmax;
    if (t == pos_col) pos_sh = logit;
    __syncthreads();
    const float mx = fmaxf(fmaxf(red[0], red[1]), fmaxf(red[2], red[3]));
    const float pos = pos_sh;
    const float ws = waveSum(valid ? wgt * expf(logit - mx) : 0.f);
    if (lane == 0) red[4 + wid] = ws;
    __syncthreads();
    if (t == 0) {
      const float s = red[4] + red[5] + red[6] + red[7];
      part += (mx + logf(s)) - pos;
    }
    __syncthreads();
  }
  if (t == 0) partial[blockIdx.x] = part;
}

// ---------------------------------------------------------------------------
// Kernel 3 (MFMA v3): inst_pred[b][n][p] = sum_c mw[b][c][n] * x[b][c][p]
// 1KB-SINGLE-ROW READ BURSTS: per c-phase (32 rows), wave w streams 8
// CONSECUTIVE rows, 1.28 KB each, as full-wave float4 instrs (1KB + 256B).
// LDS is linear [c][p] bf16 (conflict-free writes); B-frags assembled from
// 8x ds_read_u16 (lane pairs share banks = free). A-frag/MFMA/C-layout are
// identical to the R9-verified mapping.
// ---------------------------------------------------------------------------
typedef __attribute__((ext_vector_type(8))) short bf16x8;
typedef __attribute__((ext_vector_type(4))) float f32x4;

__device__ __forceinline__ uint32_t bf16rne(float f) {
  uint32_t u = __builtin_bit_cast(uint32_t, f);
  return (u + 0x7FFFu + ((u >> 16) & 1u)) >> 16;
}

__global__ __launch_bounds__(256, 3) void k_pred(const float* __restrict__ x,
                                                 const float* __restrict__ mw,
                                                 const float* __restrict__ partial,
                                                 float* __restrict__ out) {
  __shared__ __align__(16) unsigned short xl[CHK][PT];  // 20 KB bf16, [c][p]

  const int b = blockIdx.y;
  const int p0 = blockIdx.x * PT;
  const int u = threadIdx.x;
  const int l = u & 63;        // lane
  const int w = u >> 6;        // wave 0..3 -> n-subtile base 16*w
  const int ln = l & 15, lg = l >> 4;

  const float* xb  = x  + (size_t)b * CO * HW_TOT;
  const float* mwb = mw + (size_t)b * CO * NN;

  // ---- A-fragments from mw (L1/L2-hot), n clamped; same mapping as R9 ----
  bf16x8 afr[2];
  #pragma unroll
  for (int ks = 0; ks < 2; ++ks) {
    #pragma unroll
    for (int j = 0; j < 8; ++j) {
      const int c = ks * 32 + lg * 8 + j;
      const int n = min(16 * w + ln, NN - 1);   // rows >=50 garbage, masked at store
      afr[ks][j] = (short)bf16rne(mwb[c * NN + n]);
    }
  }

  f32x4 acc[PT / 16];  // 20 p-subtiles x f32x4, statically indexed

  #pragma unroll 1
  for (int ks = 0; ks < 2; ++ks) {
    if (ks > 0) __syncthreads();  // all waves done reading phase-0 LDS

    // ---- stage: wave w streams rows rbase..rbase+7, 1.28 KB each ----
    {
      const int rbase = ks * CHK + w * 8;
      float4 va[8];
      #pragma unroll
      for (int rr = 0; rr < 8; ++rr)
        va[rr] = *reinterpret_cast<const float4*>(
            xb + (size_t)(rbase + rr) * HW_TOT + p0 + 4 * l);
      float4 vt[8];
      if (l < 16) {
        #pragma unroll
        for (int rr = 0; rr < 8; ++rr)
          vt[rr] = *reinterpret_cast<const float4*>(
              xb + (size_t)(rbase + rr) * HW_TOT + p0 + 256 + 4 * l);
      }
      #pragma unroll
      for (int rr = 0; rr < 8; ++rr) {
        ushort4 s;
        s.x = (unsigned short)bf16rne(va[rr].x);
        s.y = (unsigned short)bf16rne(va[rr].y);
        s.z = (unsigned short)bf16rne(va[rr].z);
        s.w = (unsigned short)bf16rne(va[rr].w);
        *reinterpret_cast<ushort4*>(&xl[w * 8 + rr][4 * l]) = s;
      }
      if (l < 16) {
        #pragma unroll
        for (int rr = 0; rr < 8; ++rr) {
          ushort4 s;
          s.x = (unsigned short)bf16rne(vt[rr].x);
          s.y = (unsigned short)bf16rne(vt[rr].y);
          s.z = (unsigned short)bf16rne(vt[rr].z);
          s.w = (unsigned short)bf16rne(vt[rr].w);
          *reinterpret_cast<ushort4*>(&xl[w * 8 + rr][256 + 4 * l]) = s;
        }
      }
    }
    __syncthreads();

    if (ks == 0) {
      #pragma unroll
      for (int q = 0; q < PT / 16; ++q) acc[q] = (f32x4){0.f, 0.f, 0.f, 0.f};
    }

    // ---- MFMA: B-frag = 8 x ds_read_u16 (c-column at fixed p) ----
    #pragma unroll
    for (int q = 0; q < PT / 16; ++q) {
      bf16x8 bfr;
      #pragma unroll
      for (int j = 0; j < 8; ++j)
        bfr[j] = (short)xl[lg * 8 + j][q * 16 + ln];
      acc[q] = __builtin_amdgcn_mfma_f32_16x16x32_bf16(afr[ks], bfr, acc[q], 0, 0, 0);
    }
  }

  // ---- epilogue: each n-row's PT pixels come from one wave ----
  float* ob = out + (size_t)b * NN * HW_TOT + p0;
  #pragma unroll
  for (int i = 0; i < 4; ++i) {
    const int n = 16 * w + 4 * lg + i;
    if (n < NN) {
      float* orow = ob + (size_t)n * HW_TOT + ln;
      #pragma unroll
      for (int q = 0; q < PT / 16; ++q)
        orow[q * 16] = acc[q][i];
    }
  }

  // Loss finalize.
  if (blockIdx.x == 0 && b == 0 && u == 0) {
    float s = 0.f;
    #pragma unroll
    for (int i = 0; i < 16; ++i) s += partial[i];
    out[(size_t)NBF * NN * HW_TOT] = s * (1.0f / KK);  // sum_b mean_k
  }
}

// ---------------------------------------------------------------------------
extern "C" void kernel_launch(void* const* d_in, const int* in_sizes, int n_in,
                              void* d_out, int out_size, void* d_ws, size_t ws_size,
                              hipStream_t stream) {
  const float* x        = (const float*)d_in[0];
  const float* idx_feat = (const float*)d_in[1];
  const float* weight   = (const float*)d_in[2];
  const float* bias     = (const float*)d_in[3];
  float* out = (float*)d_out;

  float* mw = (float*)d_ws;                 // 25600 floats
  float* partial = mw + NBF * CO * NN;      // 16 floats

  hipLaunchKernelGGL(k_mw, dim3((NBF * CO * NN + 255) / 256), dim3(256), 0, stream,
                     idx_feat, weight, bias, mw);
  hipLaunchKernelGGL(k_loss, dim3(16), dim3(256), 0, stream, mw, partial);
  hipLaunchKernelGGL(k_pred, dim3(HW_TOT / PT, NBF), dim3(256), 0, stream,
                     x, mw, partial, out);
}

// Round 13
// 86.917 us; speedup vs baseline: 1.0803x; 1.0803x over previous
//
#include <hip/hip_runtime.h>
#include <stdint.h>
#include <float.h>
#include <math.h>

// Problem constants (b_n=2, f_num=4, N=50, C_in=256, C=64, h=200, w=336)
#define HW_TOT 67200   // h*w = 320 * 210
#define NBF 8          // n = b_n*f_num
#define CO 64          // C
#define CI 256         // C_in
#define NN 50          // N
#define KK 200         // K = N*f_num
#define BN 2           // b_n
#define TILES 5        // 64-px tiles swept per block
#define PT (64 * TILES)// 320 px per block

// ---------------------------------------------------------------------------
// Threefry-2x32, 20 rounds (JAX partitionable threefry semantics) — verified R1
// ---------------------------------------------------------------------------
__device__ __forceinline__ uint32_t rotl32(uint32_t v, int n) {
  return (v << n) | (v >> (32 - n));
}

__device__ void tf2x32(uint32_t k0, uint32_t k1, uint32_t x0, uint32_t x1,
                       uint32_t& o0, uint32_t& o1) {
  const uint32_t ks2 = k0 ^ k1 ^ 0x1BD11BDAu;
  x0 += k0; x1 += k1;
  x0 += x1; x1 = rotl32(x1, 13); x1 ^= x0;
  x0 += x1; x1 = rotl32(x1, 15); x1 ^= x0;
  x0 += x1; x1 = rotl32(x1, 26); x1 ^= x0;
  x0 += x1; x1 = rotl32(x1, 6);  x1 ^= x0;
  x0 += k1; x1 += ks2 + 1u;
  x0 += x1; x1 = rotl32(x1, 17); x1 ^= x0;
  x0 += x1; x1 = rotl32(x1, 29); x1 ^= x0;
  x0 += x1; x1 = rotl32(x1, 16); x1 ^= x0;
  x0 += x1; x1 = rotl32(x1, 24); x1 ^= x0;
  x0 += ks2; x1 += k0 + 2u;
  x0 += x1; x1 = rotl32(x1, 13); x1 ^= x0;
  x0 += x1; x1 = rotl32(x1, 15); x1 ^= x0;
  x0 += x1; x1 = rotl32(x1, 26); x1 ^= x0;
  x0 += x1; x1 = rotl32(x1, 6);  x1 ^= x0;
  x0 += k0; x1 += k1 + 3u;
  x0 += x1; x1 = rotl32(x1, 17); x1 ^= x0;
  x0 += x1; x1 = rotl32(x1, 29); x1 ^= x0;
  x0 += x1; x1 = rotl32(x1, 16); x1 ^= x0;
  x0 += x1; x1 = rotl32(x1, 24); x1 ^= x0;
  x0 += k1; x1 += ks2 + 4u;
  x0 += x1; x1 = rotl32(x1, 13); x1 ^= x0;
  x0 += x1; x1 = rotl32(x1, 15); x1 ^= x0;
  x0 += x1; x1 = rotl32(x1, 26); x1 ^= x0;
  x0 += x1; x1 = rotl32(x1, 6);  x1 ^= x0;
  o0 = x0 + ks2;
  o1 = x1 + k0 + 5u;
}

__device__ int jax_r(int b, int k) {
  uint32_t k1a, k1b, k2a, k2b, h0, h1, l0, l1;
  tf2x32(0u, 42u, 0u, 0u, k1a, k1b);  // split: subkey 0
  tf2x32(0u, 42u, 0u, 1u, k2a, k2b);  // split: subkey 1
  const uint32_t idx = (uint32_t)(b * KK + k);
  tf2x32(k1a, k1b, 0u, idx, h0, h1);
  tf2x32(k2a, k2b, 0u, idx, l0, l1);
  const uint32_t hb = h0 ^ h1, lb = l0 ^ l1;
  return (int)(((hb % 3u) + (lb % 3u)) % 3u);
}

// ---------------------------------------------------------------------------
// Kernel 1: mw[b][d][n] = bias[d] + sum_ci idx_feat[b][ci][n] * weight[d][ci]
// ---------------------------------------------------------------------------
__global__ __launch_bounds__(256) void k_mw(const float* __restrict__ idx_feat,
                                            const float* __restrict__ weight,
                                            const float* __restrict__ bias,
                                            float* __restrict__ mw) {
  const int tid = blockIdx.x * 256 + threadIdx.x;
  if (tid >= NBF * CO * NN) return;
  const int n = tid % NN;
  const int rest = tid / NN;
  const int d = rest % CO;
  const int b = rest / CO;
  float acc = bias[d];
  const float* feat = idx_feat + (size_t)(b * CI) * NN + n;  // stride NN per ci
  const float* wrow = weight + d * CI;
  #pragma unroll 8
  for (int ci = 0; ci < CI; ++ci)
    acc = fmaf(feat[ci * NN], wrow[ci], acc);
  mw[tid] = acc;  // layout [b][d][n]
}

// ---------------------------------------------------------------------------
// Kernel 2: contrastive loss partials. 16 blocks = 2 b * 8 chunks of 25 k.
// ---------------------------------------------------------------------------
__device__ __forceinline__ float waveMax(float v) {
  #pragma unroll
  for (int o = 32; o > 0; o >>= 1) v = fmaxf(v, __shfl_down(v, o));
  return v;
}
__device__ __forceinline__ float waveSum(float v) {
  #pragma unroll
  for (int o = 32; o > 0; o >>= 1) v += __shfl_down(v, o);
  return v;
}

__global__ __launch_bounds__(256) void k_loss(const float* __restrict__ mw,
                                              float* __restrict__ partial) {
  __shared__ __align__(16) float m_lds[KK][68];  // padded rows (54.4 KB)
  __shared__ float red[8];
  __shared__ float pos_sh;
  __shared__ int rvals[32];

  const int b = blockIdx.x >> 3;
  const int chunk = blockIdx.x & 7;
  const int t = threadIdx.x;
  const int wid = t >> 6, lane = t & 63;
  const int kbase = chunk * 25;

  if (t < 25) rvals[t] = jax_r(b, kbase + t);

  float row[CO];
  if (t < KK) {
    const int f = t & 3, ni = t >> 2;
    const float* src = mw + (size_t)((b * 4 + f) * CO) * NN + ni;  // stride NN per c
    float ssq = 0.f;
    #pragma unroll
    for (int c = 0; c < CO; ++c) { const float v = src[c * NN]; row[c] = v; ssq += v * v; }
    const float inv = 1.0f / fmaxf(sqrtf(ssq), 1e-12f);
    #pragma unroll
    for (int c = 0; c < CO; ++c) { row[c] *= inv; m_lds[t][c] = row[c]; }
  }
  __syncthreads();

  float part = 0.f;
  for (int kk = 0; kk < 25; ++kk) {
    const int k = kbase + kk;
    const int g = k >> 2, fo = k & 3;
    const int r = rvals[kk];
    const int pos_off = (r >= fo) ? r + 1 : r;
    const int pos_col = (g << 2) + pos_off;
    const int last_neg = (g == NN - 1) ? (KK - 5) : (KK - 1);  // 195 or 199

    float dot = 0.f;
    if (t < KK) {
      const float4* mk = reinterpret_cast<const float4*>(&m_lds[k][0]);  // broadcast
      #pragma unroll
      for (int c4 = 0; c4 < 16; ++c4) {
        const float4 a = mk[c4];
        dot = fmaf(a.x, row[4 * c4 + 0], dot);
        dot = fmaf(a.y, row[4 * c4 + 1], dot);
        dot = fmaf(a.z, row[4 * c4 + 2], dot);
        dot = fmaf(a.w, row[4 * c4 + 3], dot);
      }
    }
    const float logit = dot * (1.0f / 0.07f);

    float wgt = 0.f;
    if (t < KK) {
      if (t == pos_col) wgt = 1.f;
      else if ((t >> 2) != g) wgt = (t == last_neg) ? 4.f : 1.f;
    }
    const bool valid = wgt > 0.f;

    const float wmax = waveMax(valid ? logit : -FLT_MAX);
    if (lane == 0) red[wid] = wmax;
    if (t == pos_col) pos_sh = logit;
    __syncthreads();
    const float mx = fmaxf(fmaxf(red[0], red[1]), fmaxf(red[2], red[3]));
    const float pos = pos_sh;
    const float ws = waveSum(valid ? wgt * expf(logit - mx) : 0.f);
    if (lane == 0) red[4 + wid] = ws;
    __syncthreads();
    if (t == 0) {
      const float s = red[4] + red[5] + red[6] + red[7];
      part += (mx + logf(s)) - pos;
    }
    __syncthreads();
  }
  if (t == 0) partial[blockIdx.x] = part;
}

// ---------------------------------------------------------------------------
// Kernel 3 (MFMA v4): R10's proven compute structure (TILES sweep, 8 KB
// input LDS, same MFMA mapping) + WRITE-PAGE FIX: accumulate the block's
// whole 50x320 output in LDS (64 KB) and store ONCE at block end as
// contiguous 1.28 KB-per-row NT float4 wave-stores. Each out DRAM page is
// visited once with >=1.28 KB (vs 256 B per visit in R9-R11).
// ---------------------------------------------------------------------------
typedef __attribute__((ext_vector_type(8))) short bf16x8;
typedef __attribute__((ext_vector_type(4))) float f32x4;

__device__ __forceinline__ uint32_t bf16rne(float f) {
  uint32_t u = __builtin_bit_cast(uint32_t, f);
  return (u + 0x7FFFu + ((u >> 16) & 1u)) >> 16;
}

__global__ __launch_bounds__(256, 4) void k_pred(const float* __restrict__ x,
                                                 const float* __restrict__ mw,
                                                 const float* __restrict__ partial,
                                                 float* __restrict__ out) {
  __shared__ __align__(16) char lds[64 * 128];     // in-tile [p][c] bf16, swizzled
  __shared__ __align__(16) float olds[NN][PT];     // 64 KB block output

  const int b = blockIdx.y;
  const int u = threadIdx.x;
  const int l = u & 63;        // lane
  const int w = u >> 6;        // wave 0..3 -> n-subtile base 16*w
  const int ln = l & 15, lg = l >> 4;

  const float* xb  = x  + (size_t)b * CO * HW_TOT;
  const float* mwb = mw + (size_t)b * CO * NN;

  const int sc0 = 4 * (u >> 4);   // c rows sc0..sc0+3
  const int sp0 = 4 * (u & 15);   // local p cols sp0..sp0+3
  const int pbase = blockIdx.x * PT;

  // ---- A-fragments from mw (L1/L2-hot), once per block; n clamped ----
  bf16x8 afr[2];
  #pragma unroll
  for (int ks = 0; ks < 2; ++ks) {
    #pragma unroll
    for (int j = 0; j < 8; ++j) {
      const int c = ks * 32 + lg * 8 + j;
      const int n = min(16 * w + ln, NN - 1);   // rows >=50 garbage, masked later
      afr[ks][j] = (short)bf16rne(mwb[c * NN + n]);
    }
  }

  // ---- prologue: load tile 0 (4 independent coalesced float4) ----
  float4 v0, v1, v2, v3;
  {
    const float* src = xb + (size_t)sc0 * HW_TOT + pbase + sp0;
    v0 = *reinterpret_cast<const float4*>(src);
    v1 = *reinterpret_cast<const float4*>(src + HW_TOT);
    v2 = *reinterpret_cast<const float4*>(src + 2 * (size_t)HW_TOT);
    v3 = *reinterpret_cast<const float4*>(src + 3 * (size_t)HW_TOT);
  }

  #pragma unroll 1
  for (int t = 0; t < TILES; ++t) {
    if (t > 0) __syncthreads();  // all waves done reading prev tile's LDS

    // ---- transpose 4x4 micro-tile -> bf16 -> swizzled LDS (R10 exact) ----
    {
      const float c0s[4] = {v0.x, v1.x, v2.x, v3.x};
      const float c1s[4] = {v0.y, v1.y, v2.y, v3.y};
      const float c2s[4] = {v0.z, v1.z, v2.z, v3.z};
      const float c3s[4] = {v0.w, v1.w, v2.w, v3.w};
      const float* cols[4] = {c0s, c1s, c2s, c3s};
      #pragma unroll
      for (int s = 0; s < 4; ++s) {
        const float* cv = cols[s];
        const uint32_t lo = bf16rne(cv[0]) | (bf16rne(cv[1]) << 16);
        const uint32_t hi = bf16rne(cv[2]) | (bf16rne(cv[3]) << 16);
        const int row = sp0 + s;
        const int wb = (row * 128 + sc0 * 2) ^ ((row & 7) << 4);
        *reinterpret_cast<uint2*>(lds + wb) = make_uint2(lo, hi);
      }
    }
    __syncthreads();

    // ---- issue next tile's loads (overlap MFMA below) ----
    if (t + 1 < TILES) {
      const float* src = xb + (size_t)sc0 * HW_TOT + pbase + (t + 1) * 64 + sp0;
      v0 = *reinterpret_cast<const float4*>(src);
      v1 = *reinterpret_cast<const float4*>(src + HW_TOT);
      v2 = *reinterpret_cast<const float4*>(src + 2 * (size_t)HW_TOT);
      v3 = *reinterpret_cast<const float4*>(src + 3 * (size_t)HW_TOT);
    }

    // ---- MFMA: 2 k-steps x 4 p-subtiles (R10 exact) ----
    f32x4 acc[4];
    #pragma unroll
    for (int q = 0; q < 4; ++q) acc[q] = (f32x4){0.f, 0.f, 0.f, 0.f};

    #pragma unroll
    for (int ks = 0; ks < 2; ++ks) {
      #pragma unroll
      for (int q = 0; q < 4; ++q) {
        const int row = q * 16 + ln;             // local p
        const int rb = (row * 128 + ks * 64 + lg * 16) ^ ((ln & 7) << 4);
        const uint4 raw = *reinterpret_cast<const uint4*>(lds + rb);
        const bf16x8 bfr = __builtin_bit_cast(bf16x8, raw);
        acc[q] = __builtin_amdgcn_mfma_f32_16x16x32_bf16(afr[ks], bfr, acc[q], 0, 0, 0);
      }
    }

    // ---- acc -> olds (per-wave rows disjoint; no extra barrier needed) ----
    #pragma unroll
    for (int i = 0; i < 4; ++i) {
      const int n = 16 * w + 4 * lg + i;
      if (n < NN) {
        #pragma unroll
        for (int q = 0; q < 4; ++q)
          olds[n][t * 64 + q * 16 + ln] = acc[q][i];
      }
    }
  }

  __syncthreads();  // olds complete

  // ---- linear store pass: contiguous 1.28 KB per out row, NT f32x4 ----
  {
    float* ob = out + (size_t)b * NN * HW_TOT + pbase;
    #pragma unroll 1
    for (int f = u; f < NN * (PT / 4); f += 256) {
      const int row = f / (PT / 4);
      const int c4 = f % (PT / 4);
      const f32x4 v = *reinterpret_cast<const f32x4*>(&olds[row][c4 * 4]);
      __builtin_nontemporal_store(v,
          reinterpret_cast<f32x4*>(ob + (size_t)row * HW_TOT + c4 * 4));
    }
  }

  // Loss finalize.
  if (blockIdx.x == 0 && b == 0 && u == 0) {
    float s = 0.f;
    #pragma unroll
    for (int i = 0; i < 16; ++i) s += partial[i];
    out[(size_t)NBF * NN * HW_TOT] = s * (1.0f / KK);  // sum_b mean_k
  }
}

// ---------------------------------------------------------------------------
extern "C" void kernel_launch(void* const* d_in, const int* in_sizes, int n_in,
                              void* d_out, int out_size, void* d_ws, size_t ws_size,
                              hipStream_t stream) {
  const float* x        = (const float*)d_in[0];
  const float* idx_feat = (const float*)d_in[1];
  const float* weight   = (const float*)d_in[2];
  const float* bias     = (const float*)d_in[3];
  float* out = (float*)d_out;

  float* mw = (float*)d_ws;                 // 25600 floats
  float* partial = mw + NBF * CO * NN;      // 16 floats

  hipLaunchKernelGGL(k_mw, dim3((NBF * CO * NN + 255) / 256), dim3(256), 0, stream,
                     idx_feat, weight, bias, mw);
  hipLaunchKernelGGL(k_loss, dim3(16), dim3(256), 0, stream, mw, partial);
  hipLaunchKernelGGL(k_pred, dim3(HW_TOT / PT, NBF), dim3(256), 0, stream,
                     x, mw, partial, out);
}

// Round 14
// 85.307 us; speedup vs baseline: 1.1007x; 1.0189x over previous
//
#include <hip/hip_runtime.h>
#include <stdint.h>
#include <float.h>
#include <math.h>

// Problem constants (b_n=2, f_num=4, N=50, C_in=256, C=64, h=200, w=336)
#define HW_TOT 67200   // h*w = 1050 * 64
#define NBF 8          // n = b_n*f_num
#define CO 64          // C
#define CI 256         // C_in
#define NN 50          // N
#define KK 200         // K = N*f_num
#define BN 2           // b_n

// ---------------------------------------------------------------------------
// Threefry-2x32, 20 rounds (JAX partitionable threefry semantics) — verified R1
// ---------------------------------------------------------------------------
__device__ __forceinline__ uint32_t rotl32(uint32_t v, int n) {
  return (v << n) | (v >> (32 - n));
}

__device__ void tf2x32(uint32_t k0, uint32_t k1, uint32_t x0, uint32_t x1,
                       uint32_t& o0, uint32_t& o1) {
  const uint32_t ks2 = k0 ^ k1 ^ 0x1BD11BDAu;
  x0 += k0; x1 += k1;
  x0 += x1; x1 = rotl32(x1, 13); x1 ^= x0;
  x0 += x1; x1 = rotl32(x1, 15); x1 ^= x0;
  x0 += x1; x1 = rotl32(x1, 26); x1 ^= x0;
  x0 += x1; x1 = rotl32(x1, 6);  x1 ^= x0;
  x0 += k1; x1 += ks2 + 1u;
  x0 += x1; x1 = rotl32(x1, 17); x1 ^= x0;
  x0 += x1; x1 = rotl32(x1, 29); x1 ^= x0;
  x0 += x1; x1 = rotl32(x1, 16); x1 ^= x0;
  x0 += x1; x1 = rotl32(x1, 24); x1 ^= x0;
  x0 += ks2; x1 += k0 + 2u;
  x0 += x1; x1 = rotl32(x1, 13); x1 ^= x0;
  x0 += x1; x1 = rotl32(x1, 15); x1 ^= x0;
  x0 += x1; x1 = rotl32(x1, 26); x1 ^= x0;
  x0 += x1; x1 = rotl32(x1, 6);  x1 ^= x0;
  x0 += k0; x1 += k1 + 3u;
  x0 += x1; x1 = rotl32(x1, 17); x1 ^= x0;
  x0 += x1; x1 = rotl32(x1, 29); x1 ^= x0;
  x0 += x1; x1 = rotl32(x1, 16); x1 ^= x0;
  x0 += x1; x1 = rotl32(x1, 24); x1 ^= x0;
  x0 += k1; x1 += ks2 + 4u;
  x0 += x1; x1 = rotl32(x1, 13); x1 ^= x0;
  x0 += x1; x1 = rotl32(x1, 15); x1 ^= x0;
  x0 += x1; x1 = rotl32(x1, 26); x1 ^= x0;
  x0 += x1; x1 = rotl32(x1, 6);  x1 ^= x0;
  o0 = x0 + ks2;
  o1 = x1 + k0 + 5u;
}

__device__ int jax_r(int b, int k) {
  uint32_t k1a, k1b, k2a, k2b, h0, h1, l0, l1;
  tf2x32(0u, 42u, 0u, 0u, k1a, k1b);  // split: subkey 0
  tf2x32(0u, 42u, 0u, 1u, k2a, k2b);  // split: subkey 1
  const uint32_t idx = (uint32_t)(b * KK + k);
  tf2x32(k1a, k1b, 0u, idx, h0, h1);
  tf2x32(k2a, k2b, 0u, idx, l0, l1);
  const uint32_t hb = h0 ^ h1, lb = l0 ^ l1;
  return (int)(((hb % 3u) + (lb % 3u)) % 3u);
}

// ---------------------------------------------------------------------------
// Kernel 1: mw[b][d][n] = bias[d] + sum_ci idx_feat[b][ci][n] * weight[d][ci]
// ---------------------------------------------------------------------------
__global__ __launch_bounds__(256) void k_mw(const float* __restrict__ idx_feat,
                                            const float* __restrict__ weight,
                                            const float* __restrict__ bias,
                                            float* __restrict__ mw) {
  const int tid = blockIdx.x * 256 + threadIdx.x;
  if (tid >= NBF * CO * NN) return;
  const int n = tid % NN;
  const int rest = tid / NN;
  const int d = rest % CO;
  const int b = rest / CO;
  float acc = bias[d];
  const float* feat = idx_feat + (size_t)(b * CI) * NN + n;  // stride NN per ci
  const float* wrow = weight + d * CI;
  #pragma unroll 8
  for (int ci = 0; ci < CI; ++ci)
    acc = fmaf(feat[ci * NN], wrow[ci], acc);
  mw[tid] = acc;  // layout [b][d][n]
}

// ---------------------------------------------------------------------------
// Kernel 2: contrastive loss partials. 16 blocks = 2 b * 8 chunks of 25 k.
// ---------------------------------------------------------------------------
__device__ __forceinline__ float waveMax(float v) {
  #pragma unroll
  for (int o = 32; o > 0; o >>= 1) v = fmaxf(v, __shfl_down(v, o));
  return v;
}
__device__ __forceinline__ float waveSum(float v) {
  #pragma unroll
  for (int o = 32; o > 0; o >>= 1) v += __shfl_down(v, o);
  return v;
}

__global__ __launch_bounds__(256) void k_loss(const float* __restrict__ mw,
                                              float* __restrict__ partial) {
  __shared__ __align__(16) float m_lds[KK][68];  // padded rows (54.4 KB)
  __shared__ float red[8];
  __shared__ float pos_sh;
  __shared__ int rvals[32];

  const int b = blockIdx.x >> 3;
  const int chunk = blockIdx.x & 7;
  const int t = threadIdx.x;
  const int wid = t >> 6, lane = t & 63;
  const int kbase = chunk * 25;

  if (t < 25) rvals[t] = jax_r(b, kbase + t);

  float row[CO];
  if (t < KK) {
    const int f = t & 3, ni = t >> 2;
    const float* src = mw + (size_t)((b * 4 + f) * CO) * NN + ni;  // stride NN per c
    float ssq = 0.f;
    #pragma unroll
    for (int c = 0; c < CO; ++c) { const float v = src[c * NN]; row[c] = v; ssq += v * v; }
    const float inv = 1.0f / fmaxf(sqrtf(ssq), 1e-12f);
    #pragma unroll
    for (int c = 0; c < CO; ++c) { row[c] *= inv; m_lds[t][c] = row[c]; }
  }
  __syncthreads();

  float part = 0.f;
  for (int kk = 0; kk < 25; ++kk) {
    const int k = kbase + kk;
    const int g = k >> 2, fo = k & 3;
    const int r = rvals[kk];
    const int pos_off = (r >= fo) ? r + 1 : r;
    const int pos_col = (g << 2) + pos_off;
    const int last_neg = (g == NN - 1) ? (KK - 5) : (KK - 1);  // 195 or 199

    float dot = 0.f;
    if (t < KK) {
      const float4* mk = reinterpret_cast<const float4*>(&m_lds[k][0]);  // broadcast
      #pragma unroll
      for (int c4 = 0; c4 < 16; ++c4) {
        const float4 a = mk[c4];
        dot = fmaf(a.x, row[4 * c4 + 0], dot);
        dot = fmaf(a.y, row[4 * c4 + 1], dot);
        dot = fmaf(a.z, row[4 * c4 + 2], dot);
        dot = fmaf(a.w, row[4 * c4 + 3], dot);
      }
    }
    const float logit = dot * (1.0f / 0.07f);

    float wgt = 0.f;
    if (t < KK) {
      if (t == pos_col) wgt = 1.f;
      else if ((t >> 2) != g) wgt = (t == last_neg) ? 4.f : 1.f;
    }
    const bool valid = wgt > 0.f;

    const float wmax = waveMax(valid ? logit : -FLT_MAX);
    if (lane == 0) red[wid] = wmax;
    if (t == pos_col) pos_sh = logit;
    __syncthreads();
    const float mx = fmaxf(fmaxf(red[0], red[1]), fmaxf(red[2], red[3]));
    const float pos = pos_sh;
    const float ws = waveSum(valid ? wgt * expf(logit - mx) : 0.f);
    if (lane == 0) red[4 + wid] = ws;
    __syncthreads();
    if (t == 0) {
      const float s = red[4] + red[5] + red[6] + red[7];
      part += (mx + logf(s)) - pos;
    }
    __syncthreads();
  }
  if (t == 0) partial[blockIdx.x] = part;
}

// ---------------------------------------------------------------------------
// Kernel 3 (MFMA v5): WAVE-AUTONOMOUS, ZERO-BARRIER.
// One 64-thread block (= one wave) owns a full 64-px strip:
//   - 64 independent 256B row loads (16 KB in flight, progressive vmcnt)
//   - bf16 -> wave-private LDS [64px][68c] (pad-68: stride 136B, 2-way free)
//   - R9-verified MFMA mapping (A = mw gather, B = ds_read_b128, 32 MFMA)
//   - store-transpose via same LDS, 2x32-row chunks (same-wave lgkmcnt only)
//   - 50 NT 256B row stores
// NO __syncthreads anywhere: no vmcnt(0) barrier drain -> waves keep loads
// in flight continuously (the structural difference vs R1..R13, per the
// fill/copy 6.3-7 TB/s reference kernels which also have no barriers).
// ---------------------------------------------------------------------------
typedef __attribute__((ext_vector_type(8))) short bf16x8;
typedef __attribute__((ext_vector_type(4))) float f32x4;

__device__ __forceinline__ uint32_t bf16rne(float f) {
  uint32_t u = __builtin_bit_cast(uint32_t, f);
  return (u + 0x7FFFu + ((u >> 16) & 1u)) >> 16;
}

__global__ __launch_bounds__(64, 3) void k_pred(const float* __restrict__ x,
                                                const float* __restrict__ mw,
                                                const float* __restrict__ partial,
                                                float* __restrict__ out) {
  __shared__ __align__(16) char wlds[64 * 136];  // 8704 B, wave-private

  const int b = blockIdx.y;
  const int p0 = blockIdx.x * 64;
  const int l = threadIdx.x;          // 0..63
  const int ln = l & 15, lg = l >> 4;

  const float* xb  = x  + (size_t)b * CO * HW_TOT + p0 + l;
  const float* mwb = mw + (size_t)b * CO * NN;

  // ---- A-fragments: mw gather (L1/L2-hot, 12.8 KB/b), consumed first ----
  bf16x8 afr[4][2];
  #pragma unroll
  for (int ns = 0; ns < 4; ++ns) {
    const int n = min(ns * 16 + ln, NN - 1);   // rows >=50 dup row 49, masked at store
    #pragma unroll
    for (int ks = 0; ks < 2; ++ks)
      #pragma unroll
      for (int j = 0; j < 8; ++j)
        afr[ns][ks][j] = (short)bf16rne(mwb[(ks * 32 + lg * 8 + j) * NN + n]);
  }

  // ---- issue all 64 independent x-row loads (256B coalesced each) ----
  float xr[64];
  #pragma unroll
  for (int c = 0; c < 64; ++c)
    xr[c] = xb[(size_t)c * HW_TOT];

  // ---- convert + transposed LDS write: [px=l][c], stride 136B (pad 68) ----
  // bank(dword) = (34*l + c/2) % 32 = (2l + c/2) % 32 -> 2 lanes/bank = free
  #pragma unroll
  for (int c = 0; c < 64; c += 2) {
    const uint32_t pk = bf16rne(xr[c]) | (bf16rne(xr[c + 1]) << 16);
    *reinterpret_cast<uint32_t*>(wlds + l * 136 + c * 2) = pk;
  }
  // same-wave producer->consumer: compiler orders via lgkmcnt (no barrier)

  // ---- MFMA: 2 k-steps x 4 p-subtiles x 4 n-subtiles ----
  f32x4 acc[4][4];
  #pragma unroll
  for (int ns = 0; ns < 4; ++ns)
    #pragma unroll
    for (int q = 0; q < 4; ++q) acc[ns][q] = (f32x4){0.f, 0.f, 0.f, 0.f};

  #pragma unroll
  for (int ks = 0; ks < 2; ++ks) {
    #pragma unroll
    for (int q = 0; q < 4; ++q) {
      const bf16x8 bfr = *reinterpret_cast<const bf16x8*>(
          wlds + (q * 16 + ln) * 136 + (ks * 32 + lg * 8) * 2);
      #pragma unroll
      for (int ns = 0; ns < 4; ++ns)
        acc[ns][q] = __builtin_amdgcn_mfma_f32_16x16x32_bf16(afr[ns][ks], bfr,
                                                             acc[ns][q], 0, 0, 0);
    }
  }

  // ---- stores via in-LDS transpose, 2 chunks of 32 n-rows (no barrier) ----
  asm volatile("s_waitcnt lgkmcnt(0)" ::: "memory");   // all bfr reads done
  __builtin_amdgcn_sched_barrier(0);

  float* ot = reinterpret_cast<float*>(wlds);          // [32][68] f32 (8704 B)
  float* ob = out + (size_t)b * NN * HW_TOT + p0 + l;

  #pragma unroll
  for (int half = 0; half < 2; ++half) {
    // write: lane l holds (n_local = 4lg+i + 16ns, p = q*16+ln)
    // bank = (68*n + 16q + ln) % 32 -> 2-way max = free
    #pragma unroll
    for (int ns = 0; ns < 2; ++ns)
      #pragma unroll
      for (int q = 0; q < 4; ++q)
        #pragma unroll
        for (int i = 0; i < 4; ++i)
          ot[(ns * 16 + 4 * lg + i) * 68 + q * 16 + ln] = acc[half * 2 + ns][q][i];

    asm volatile("s_waitcnt lgkmcnt(0)" ::: "memory");  // writes visible to own reads
    __builtin_amdgcn_sched_barrier(0);

    #pragma unroll
    for (int r = 0; r < 32; ++r) {
      const int n = half * 32 + r;
      if (n < NN)
        __builtin_nontemporal_store(ot[r * 68 + l], ob + (size_t)n * HW_TOT);
    }

    if (half == 0) {
      asm volatile("s_waitcnt lgkmcnt(0)" ::: "memory");  // reads done before rewrite
      __builtin_amdgcn_sched_barrier(0);
    }
  }

  // Loss finalize.
  if (blockIdx.x == 0 && b == 0 && l == 0) {
    float s = 0.f;
    #pragma unroll
    for (int i = 0; i < 16; ++i) s += partial[i];
    out[(size_t)NBF * NN * HW_TOT] = s * (1.0f / KK);  // sum_b mean_k
  }
}

// ---------------------------------------------------------------------------
extern "C" void kernel_launch(void* const* d_in, const int* in_sizes, int n_in,
                              void* d_out, int out_size, void* d_ws, size_t ws_size,
                              hipStream_t stream) {
  const float* x        = (const float*)d_in[0];
  const float* idx_feat = (const float*)d_in[1];
  const float* weight   = (const float*)d_in[2];
  const float* bias     = (const float*)d_in[3];
  float* out = (float*)d_out;

  float* mw = (float*)d_ws;                 // 25600 floats
  float* partial = mw + NBF * CO * NN;      // 16 floats

  hipLaunchKernelGGL(k_mw, dim3((NBF * CO * NN + 255) / 256), dim3(256), 0, stream,
                     idx_feat, weight, bias, mw);
  hipLaunchKernelGGL(k_loss, dim3(16), dim3(256), 0, stream, mw, partial);
  hipLaunchKernelGGL(k_pred, dim3(HW_TOT / 64, NBF), dim3(64), 0, stream,
                     x, mw, partial, out);
}